// Round 4
// baseline (855.639 us; speedup 1.0000x reference)
//
#include <hip/hip_runtime.h>
#include <math.h>

#define NLEV 12
#define TSIZE (1u << 19)
#define TMASK (TSIZE - 1u)
#define DOUT 257
#define PPB 256            // points per block (fused fallback)
#define EMB 24             // L*F feature dim
#define RSTRIDE 28         // fused fallback emb row stride
#define TP 128             // points per tile in head kernel

struct ResArr { float r[NLEV]; };
typedef float __attribute__((ext_vector_type(2))) f32x2;

// ---------------------------------------------------------------------
// Per-point hash-corner computation: 8 table indices + 8 trilinear
// weights. Arithmetic order kept identical to the verified kernels.
// ---------------------------------------------------------------------
struct Corner { unsigned idx[8]; float w[8]; };

__device__ __forceinline__ void hash_corners(float rf, float px, float py, float pz,
                                             Corner& c)
{
    const float sx = px * rf, sy = py * rf, sz = pz * rf;
    const float gx = floorf(sx), gy = floorf(sy), gz = floorf(sz);
    const float tx = sx - gx, ty = sy - gy, tz = sz - gz;
    const unsigned ix = (unsigned)gx, iy = (unsigned)gy, iz = (unsigned)gz;
    // primes: {1, 2654435761, 805459861}; uint32 wraparound
    const unsigned hx0 = ix,               hx1 = ix + 1u;
    const unsigned hy0 = iy * 2654435761u, hy1 = hy0 + 2654435761u;
    const unsigned hz0 = iz * 805459861u,  hz1 = hz0 + 805459861u;
    c.idx[0] = (hx0 ^ hy0 ^ hz0) & TMASK;
    c.idx[1] = (hx0 ^ hy0 ^ hz1) & TMASK;
    c.idx[2] = (hx0 ^ hy1 ^ hz0) & TMASK;
    c.idx[3] = (hx0 ^ hy1 ^ hz1) & TMASK;
    c.idx[4] = (hx1 ^ hy0 ^ hz0) & TMASK;
    c.idx[5] = (hx1 ^ hy0 ^ hz1) & TMASK;
    c.idx[6] = (hx1 ^ hy1 ^ hz0) & TMASK;
    c.idx[7] = (hx1 ^ hy1 ^ hz1) & TMASK;
    const float u0 = 1.0f - tx, u1 = tx;
    const float v0 = 1.0f - ty, v1 = ty;
    const float s0 = 1.0f - tz, s1 = tz;
    c.w[0] = (u0 * v0) * s0;
    c.w[1] = (u0 * v0) * s1;
    c.w[2] = (u0 * v1) * s0;
    c.w[3] = (u0 * v1) * s1;
    c.w[4] = (u1 * v0) * s0;
    c.w[5] = (u1 * v0) * s1;
    c.w[6] = (u1 * v1) * s0;
    c.w[7] = (u1 * v1) * s1;
}

// =====================================================================
// Phase A: level-plane hash-grid encode, ONE point per thread (round-2
// proven structure, ~290us). 1D grid dispatched level-major: all CUs
// gather into ONE level's 4 MB table == per-XCD L2 size.
// NEW: nontemporal emb2 stores. The 4 MB/level store stream previously
// write-allocated in L2, evicting half the table -> L3-latency misses.
// nt stores keep the table L2-resident (predicted: encode -> ~200-240us).
// =====================================================================
__global__ __launch_bounds__(256)
void encode_kernel(const float* __restrict__ xin,
                   const float* __restrict__ tables,
                   float2* __restrict__ emb2,
                   int N, int nbpl, ResArr res)
{
    const int lvl = blockIdx.x / nbpl;            // scalar div, once per block
    const int bx  = blockIdx.x - lvl * nbpl;
    const int p   = bx * 256 + threadIdx.x;
    if (p >= N) return;

    const float px = xin[3 * p + 0];
    const float py = xin[3 * p + 1];
    const float pz = xin[3 * p + 2];

    const float rf = res.r[lvl];
    Corner c;
    hash_corners(rf, px, py, pz, c);

    const float2* __restrict__ tab = (const float2*)tables + (size_t)lvl * TSIZE;
    // 8 fully independent gathers -> max MLP per wave
    float2 f[8];
#pragma unroll
    for (int i = 0; i < 8; ++i) f[i] = tab[c.idx[i]];

    float a = c.w[0] * f[0].x;
    float b = c.w[0] * f[0].y;
#pragma unroll
    for (int i = 1; i < 8; ++i) {
        a = fmaf(c.w[i], f[i].x, a);
        b = fmaf(c.w[i], f[i].y, b);
    }
    f32x2 v; v.x = a; v.y = b;
    __builtin_nontemporal_store(v, (f32x2*)(emb2 + (size_t)lvl * N + p));
}

// =====================================================================
// Phase B: head GEMV. 12 KB LDS tile (TP=128 points), coalesced SoA
// stage. NEW mapping: wave w owns points n === w (mod 4); lane owns 4
// output columns {l, l+64, l+128, l+192} (+ col 256 redundantly, W col
// 256 via wave-uniform scalar loads). This cuts broadcast ds_read
// traffic 4x vs all-waves-walk-all-points (25M -> 6.3M b64 reads).
// Output stores nontemporal (write-once stream). ~140 VGPR, 3 w/SIMD --
// plenty for a store-bound kernel (539 MB -> ~86us floor).
// =====================================================================
__global__ __launch_bounds__(256)
void head_kernel(const float2* __restrict__ emb2,
                 const float* __restrict__ Wm,
                 const float* __restrict__ bias,
                 float* __restrict__ out,
                 int N)
{
    __shared__ float2 sm[NLEV][TP];       // 12288 B
    const int tid  = threadIdx.x;
    const int lane = tid & 63;
    const int wv   = tid >> 6;            // wave id 0..3
    const int base = blockIdx.x * TP;
    const int nv   = min(TP, N - base);

    // wcol[k][c] = W[k][64c+lane] (coalesced); wext[k] = W[k][256] (uniform
    // -> scalar cache/SGPR); bcol[c] = bias[64c+lane].
    float wcol[EMB][4];
    float wext[EMB];
#pragma unroll
    for (int k = 0; k < EMB; ++k) {
#pragma unroll
        for (int c = 0; c < 4; ++c)
            wcol[k][c] = Wm[k * DOUT + 64 * c + lane];
        wext[k] = Wm[k * DOUT + 256];
    }
    float bcol[4];
#pragma unroll
    for (int c = 0; c < 4; ++c) bcol[c] = bias[64 * c + lane];
    const float b256 = bias[256];

    // stage emb tile: 1536 float2, 256 threads -> 6 coalesced iters
#pragma unroll
    for (int i = 0; i < (NLEV * TP) / 256; ++i) {
        const int f = i * 256 + tid;
        const int l = f >> 7;             // TP == 128
        const int n = f & (TP - 1);
        if (n < nv) sm[l][n] = emb2[(size_t)l * N + base + n];
    }
    __syncthreads();

    for (int n = wv; n < nv; n += 4) {
        float e[EMB];
#pragma unroll
        for (int l = 0; l < NLEV; ++l) {
            const float2 q = sm[l][n];    // broadcast ds_read_b64
            e[2 * l]     = q.x;
            e[2 * l + 1] = q.y;
        }
        float a0 = bcol[0], a1 = bcol[1], a2 = bcol[2], a3 = bcol[3], a4 = b256;
#pragma unroll
        for (int k = 0; k < EMB; ++k) {
            a0 = fmaf(e[k], wcol[k][0], a0);
            a1 = fmaf(e[k], wcol[k][1], a1);
            a2 = fmaf(e[k], wcol[k][2], a2);
            a3 = fmaf(e[k], wcol[k][3], a3);
            a4 = fmaf(e[k], wext[k], a4);
        }
        float* orow = out + (size_t)(base + n) * DOUT;
        __builtin_nontemporal_store(a0, orow + lane);
        __builtin_nontemporal_store(a1, orow + 64 + lane);
        __builtin_nontemporal_store(a2, orow + 128 + lane);
        __builtin_nontemporal_store(a3, orow + 192 + lane);
        if (lane == 0) __builtin_nontemporal_store(a4, orow + 256);
    }
}

// =====================================================================
// Fallback: original fused kernel (known-good), used only if the
// workspace cannot hold the 50.3 MB emb intermediate.
// =====================================================================
__global__ __launch_bounds__(256)
void hashgrid_head_kernel(const float* __restrict__ xin,
                          const float* __restrict__ tables,
                          const float* __restrict__ Wm,
                          const float* __restrict__ bias,
                          float* __restrict__ out,
                          int N, ResArr res)
{
    __shared__ float emb[PPB * RSTRIDE];
    const int tid  = threadIdx.x;
    const int base = blockIdx.x * PPB;
    const int p    = base + tid;

    float wcol[EMB];
#pragma unroll
    for (int k = 0; k < EMB; ++k) wcol[k] = Wm[k * DOUT + tid];
    const float bj = bias[tid];

    const bool extra = (tid < 64);
    float wext[EMB];
    float bext = 0.0f;
    if (extra) {
#pragma unroll
        for (int k = 0; k < EMB; ++k) wext[k] = Wm[k * DOUT + 256];
        bext = bias[256];
    }

    if (p < N) {
        const float px = xin[3 * p + 0];
        const float py = xin[3 * p + 1];
        const float pz = xin[3 * p + 2];
#pragma unroll 2
        for (int l = 0; l < NLEV; ++l) {
            const float rf = res.r[l];
            Corner c;
            hash_corners(rf, px, py, pz, c);
            const float2* __restrict__ tab = (const float2*)tables + (size_t)l * TSIZE;
            float2 f[8];
#pragma unroll
            for (int i = 0; i < 8; ++i) f[i] = tab[c.idx[i]];
            float a = c.w[0] * f[0].x;
            float b = c.w[0] * f[0].y;
#pragma unroll
            for (int i = 1; i < 8; ++i) {
                a = fmaf(c.w[i], f[i].x, a);
                b = fmaf(c.w[i], f[i].y, b);
            }
            *(float2*)&emb[tid * RSTRIDE + 2 * l] = make_float2(a, b);
        }
    }

    __syncthreads();

    const int nvalid = min(PPB, N - base);
    for (int n = 0; n < nvalid; ++n) {
        const float4* e4 = (const float4*)&emb[n * RSTRIDE];
        float4 q0 = e4[0], q1 = e4[1], q2 = e4[2], q3 = e4[3], q4 = e4[4], q5 = e4[5];
        float e[EMB] = {q0.x, q0.y, q0.z, q0.w, q1.x, q1.y, q1.z, q1.w,
                        q2.x, q2.y, q2.z, q2.w, q3.x, q3.y, q3.z, q3.w,
                        q4.x, q4.y, q4.z, q4.w, q5.x, q5.y, q5.z, q5.w};
        float acc = bj;
#pragma unroll
        for (int k = 0; k < EMB; ++k) acc = fmaf(e[k], wcol[k], acc);
        out[(size_t)(base + n) * DOUT + tid] = acc;
        if (extra) {
            float acc2 = bext;
#pragma unroll
            for (int k = 0; k < EMB; ++k) acc2 = fmaf(e[k], wext[k], acc2);
            if (tid == 0) out[(size_t)(base + n) * DOUT + 256] = acc2;
        }
    }
}

extern "C" void kernel_launch(void* const* d_in, const int* in_sizes, int n_in,
                              void* d_out, int out_size, void* d_ws, size_t ws_size,
                              hipStream_t stream) {
    const float* xin    = (const float*)d_in[0];
    const float* tables = (const float*)d_in[1];
    const float* Wm     = (const float*)d_in[2];
    const float* bias   = (const float*)d_in[3];
    float* out = (float*)d_out;
    const int N = in_sizes[0] / 3;

    // Replicate numpy: RES = floor(BASE_RES * growth**arange(L)).
    ResArr res;
    const double growth = exp((log(2048.0) - log(16.0)) / 11.0);
    for (int l = 0; l < NLEV; ++l)
        res.r[l] = (float)floor(16.0 * pow(growth, (double)l));

    const size_t need = (size_t)NLEV * (size_t)N * sizeof(float2);
    if (d_ws != nullptr && ws_size >= need) {
        float2* emb2 = (float2*)d_ws;
        const int nbpl = (N + 255) / 256;
        hipLaunchKernelGGL(encode_kernel, dim3(nbpl * NLEV), dim3(256), 0, stream,
                           xin, tables, emb2, N, nbpl, res);
        hipLaunchKernelGGL(head_kernel, dim3((N + TP - 1) / TP), dim3(256), 0, stream,
                           emb2, Wm, bias, out, N);
    } else {
        const int grid = (N + PPB - 1) / PPB;
        hipLaunchKernelGGL(hashgrid_head_kernel, dim3(grid), dim3(PPB), 0, stream,
                           xin, tables, Wm, bias, out, N, res);
    }
}